// Round 1
// baseline (303.191 us; speedup 1.0000x reference)
//
#include <hip/hip_runtime.h>
#include <math.h>

// QFCModel: avgpool(6x6) -> linear(16->4) -> 4-qubit circuit -> <Z> -> batchnorm
//
// Key identity: |psi> = U_var * |enc(f)>, U_var fixed 16x16 complex (from vparams).
// enc[j] = r_j * (-i)^popcount(j), r_j real product of cos/sin half-angles.
// Fold phase into U columns => y_i = sum_j U'[i][j] * r_j  (real multiplier).
// <Z_w> = Walsh coefficient m=1<<(3-w) of q_i = |y_i|^2 (16-lane shfl butterfly).

#define IMG_PER_BLOCK 16
#define IMG_F 784          // floats per image (28*28)
#define IMG_F4_USED 168    // float4s per image actually needed (24 rows * 28 / 4)
#define USED_F 672         // floats per image needed (24*28)
#define TOT4 (IMG_PER_BLOCK * IMG_F4_USED)  // 2688
#define ACC_SETS 64

__global__ __launch_bounds__(256) void qfc_main(
    const float* __restrict__ x,
    const float* __restrict__ W,
    const float* __restrict__ bias,
    const float* __restrict__ vparams,
    float* __restrict__ out,
    double* __restrict__ acc,   // [ACC_SETS][8]: 4 sums, 4 sumsq
    int B)
{
    __shared__ float  lds_img[IMG_PER_BLOCK * USED_F];  // 43008 B
    __shared__ float2 Uc[256];                          // U'[j][i] at Uc[j*16+i]
    __shared__ float  pooled_s[256];                    // [g][cell]
    __shared__ float  bsum[4], bsq[4];

    const int t   = threadIdx.x;
    const int blk = blockIdx.x;

    if (t < 4) { bsum[t] = 0.f; bsq[t] = 0.f; }

    // ---- Phase 1: coalesced staging of 16 images (rows 0..23 only) ----
    {
        const float4* x4   = (const float4*)x;
        float4*       lds4 = (float4*)lds_img;
        #pragma unroll
        for (int k = 0; k < 11; ++k) {
            int q = t + k * 256;
            if (q < TOT4) {
                int g   = q / IMG_F4_USED;
                int r4  = q - g * IMG_F4_USED;
                int img = blk * IMG_PER_BLOCK + g;
                if (img < B) lds4[q] = x4[img * (IMG_F / 4) + r4];
            }
        }
    }

    // ---- Phase 1b: all 256 threads build U' cooperatively ----
    // thread t holds element U[i][j], j = t>>4 (column), i = t&15 (row).
    {
        const int j = t >> 4, i = t & 15;
        float ux = (i == j) ? 1.f : 0.f, uy = 0.f;
        for (int l = 0; l < 3; ++l) {
            for (int w = 0; w < 4; ++w) {
                const float* vp = vparams + (l * 4 + w) * 3;
                const int m = 8 >> w;   // wire w = state bit (3-w)
                float s, c;
                // RX: [c, -i s; -i s, c] (symmetric -> same formula both rows)
                __sincosf(0.5f * vp[0], &s, &c);
                {
                    float ox = __shfl_xor(ux, m);
                    float oy = __shfl_xor(uy, m);
                    float nx = c * ux + s * oy;
                    float ny = c * uy - s * ox;
                    ux = nx; uy = ny;
                }
                // RY: [c, -s; s, c]
                __sincosf(0.5f * vp[1], &s, &c);
                {
                    float ox = __shfl_xor(ux, m);
                    float oy = __shfl_xor(uy, m);
                    float sg = (i & m) ? s : -s;
                    ux = c * ux + sg * ox;
                    uy = c * uy + sg * oy;
                }
                // RZ: diag(e^{-it/2}, e^{it/2})
                __sincosf(0.5f * vp[2], &s, &c);
                {
                    float sg = (i & m) ? s : -s;
                    float nx = ux * c - sg * uy;
                    float ny = uy * c + sg * ux;
                    ux = nx; uy = ny;
                }
            }
            // CNOT chain: control w (bit 3-w), target w+1 (bit 2-w)
            for (int w = 0; w < 3; ++w) {
                int mc = 8 >> w, mt = 4 >> w;
                float ox = __shfl_xor(ux, mt);
                float oy = __shfl_xor(uy, mt);
                if (i & mc) { ux = ox; uy = oy; }
            }
        }
        // fold column phase (-i)^popcount(j)
        int pc = __popc(j) & 3;
        float px, py;
        if (pc == 0)      { px =  ux; py =  uy; }
        else if (pc == 1) { px =  uy; py = -ux; }
        else if (pc == 2) { px = -ux; py = -uy; }
        else              { px = -uy; py =  ux; }
        Uc[t] = make_float2(px, py);   // Uc[j*16+i] == Uc[t]
    }
    __syncthreads();

    // ---- Phase 2: pooling. thread t -> image g = t>>4, cell = t&15 ----
    {
        const int g = t >> 4, cell = t & 15;
        const int ci = cell >> 2, cj = cell & 3;
        const float* base = lds_img + g * USED_F + ci * 6 * 28 + cj * 6;
        float sum = 0.f;
        #pragma unroll
        for (int r = 0; r < 6; ++r) {
            const float2* p2 = (const float2*)(base + r * 28);
            float2 a = p2[0], b2 = p2[1], c2 = p2[2];
            sum += a.x + a.y + b2.x + b2.y + c2.x + c2.y;
        }
        pooled_s[t] = sum * (1.0f / 36.0f);
    }
    __syncthreads();

    // ---- Phase 3: per-sample circuit. thread t -> image g, row i ----
    {
        const int g = t >> 4, i = t & 15;
        const float* pl = pooled_s + g * 16;
        float f0 = bias[0], f1 = bias[1], f2 = bias[2], f3 = bias[3];
        #pragma unroll
        for (int k = 0; k < 16; ++k) {
            float p = pl[k];
            f0 += p * W[k * 4 + 0];
            f1 += p * W[k * 4 + 1];
            f2 += p * W[k * 4 + 2];
            f3 += p * W[k * 4 + 3];
        }
        float c0, s0, c1, s1, c2, s2, c3, s3;
        __sincosf(0.5f * f0, &s0, &c0);
        __sincosf(0.5f * f1, &s1, &c1);
        __sincosf(0.5f * f2, &s2, &c2);
        __sincosf(0.5f * f3, &s3, &c3);
        // r_j = AB[j>>2] * CD[j&3]; bit3=wire0, bit2=wire1, bit1=wire2, bit0=wire3
        float AB[4] = { c0 * c1, c0 * s1, s0 * c1, s0 * s1 };
        float CD[4] = { c2 * c3, c2 * s3, s2 * c3, s2 * s3 };
        float yx = 0.f, yy = 0.f;
        #pragma unroll
        for (int j = 0; j < 16; ++j) {
            float r = AB[j >> 2] * CD[j & 3];
            float2 u = Uc[j * 16 + i];   // bank = 2*i: conflict-free
            yx += u.x * r;
            yy += u.y * r;
        }
        float q = yx * yx + yy * yy;
        // Walsh-Hadamard over the 16-lane group: lane m gets
        // sum_i (-1)^popcount(i&m) q_i. Wire w output sits at m = 1<<(3-w).
        #pragma unroll
        for (int d = 1; d <= 8; d <<= 1) {
            float o = __shfl_xor(q, d);
            q = (i & d) ? (o - q) : (o + q);
        }
        int img = blk * IMG_PER_BLOCK + g;
        if ((i == 1 || i == 2 || i == 4 || i == 8) && img < B) {
            int w = (i == 8) ? 0 : (i == 4) ? 1 : (i == 2) ? 2 : 3;
            out[img * 4 + w] = q;       // raw <Z_w>, normalized in kernel 2
            atomicAdd(&bsum[w], q);
            atomicAdd(&bsq[w],  q * q);
        }
    }
    __syncthreads();

    if (t < 4) {
        int s = blk & (ACC_SETS - 1);
        atomicAdd(&acc[s * 8 + t],     (double)bsum[t]);
        atomicAdd(&acc[s * 8 + 4 + t], (double)bsq[t]);
    }
}

__global__ __launch_bounds__(256) void qfc_bn(
    float* __restrict__ out,
    const double* __restrict__ acc,
    const float* __restrict__ gamma,
    const float* __restrict__ beta,
    int B)
{
    __shared__ double tot_s[8];
    __shared__ float  mu_s[4], sc_s[4], bt_s[4];
    const int t = threadIdx.x;
    if (t < 8) {
        double tot = 0.0;
        for (int s = 0; s < ACC_SETS; ++s) tot += acc[s * 8 + t];
        tot_s[t] = tot;
    }
    __syncthreads();
    if (t < 4) {
        double invB = 1.0 / (double)B;
        double mu   = tot_s[t] * invB;
        double var  = tot_s[4 + t] * invB - mu * mu;
        mu_s[t] = (float)mu;
        sc_s[t] = (float)(1.0 / sqrt(var + 1e-5)) * gamma[t];
        bt_s[t] = beta[t];
    }
    __syncthreads();
    int idx = blockIdx.x * blockDim.x + t;
    if (idx < B) {
        float4* o4 = (float4*)out;
        float4 v = o4[idx];
        v.x = (v.x - mu_s[0]) * sc_s[0] + bt_s[0];
        v.y = (v.y - mu_s[1]) * sc_s[1] + bt_s[1];
        v.z = (v.z - mu_s[2]) * sc_s[2] + bt_s[2];
        v.w = (v.w - mu_s[3]) * sc_s[3] + bt_s[3];
        o4[idx] = v;
    }
}

extern "C" void kernel_launch(void* const* d_in, const int* in_sizes, int n_in,
                              void* d_out, int out_size, void* d_ws, size_t ws_size,
                              hipStream_t stream) {
    const float* x       = (const float*)d_in[0];
    const float* W       = (const float*)d_in[1];
    const float* b       = (const float*)d_in[2];
    const float* vparams = (const float*)d_in[3];
    const float* gamma   = (const float*)d_in[4];
    const float* beta    = (const float*)d_in[5];
    float* out = (float*)d_out;
    const int B = in_sizes[0] / IMG_F;

    double* acc = (double*)d_ws;   // ACC_SETS*8 doubles = 4 KB
    hipMemsetAsync(acc, 0, ACC_SETS * 8 * sizeof(double), stream);

    int nblk1 = (B + IMG_PER_BLOCK - 1) / IMG_PER_BLOCK;
    qfc_main<<<nblk1, 256, 0, stream>>>(x, W, b, vparams, out, acc, B);

    int nblk2 = (B + 255) / 256;
    qfc_bn<<<nblk2, 256, 0, stream>>>(out, acc, gamma, beta, B);
}

// Round 2
// 300.493 us; speedup vs baseline: 1.0090x; 1.0090x over previous
//
#include <hip/hip_runtime.h>
#include <math.h>

// QFCModel: avgpool(6x6) -> linear(16->4) -> 4-qubit circuit -> <Z> -> batchnorm
//
// |psi> = U_var * |enc(f)>, U_var fixed 16x16 complex (from vparams).
// enc[j] = r_j * (-i)^popcount(j), r_j real product of cos/sin half-angles.
// Fold phase into U columns => y_i = sum_j U'[i][j] * r_j  (real multiplier).
// <Z_w> = Walsh coefficient m=1<<(3-w) of q_i = |y_i|^2 (16-lane shfl butterfly).
//
// R2: U' built ONCE in qfc_prep (1 block) -> d_ws; qfc_main loads it (2KB, L2)
// instead of 40 sincos + ~50 shfls per block (was ~1000 VALU instr/wave of
// pure overhead competing with the 28us memory floor).

#define IMG_PER_BLOCK 16
#define IMG_F 784          // floats per image (28*28)
#define IMG_F4_USED 168    // float4s per image actually needed (24 rows * 28 / 4)
#define USED_F 672         // floats per image needed (24*28)
#define TOT4 (IMG_PER_BLOCK * IMG_F4_USED)  // 2688
#define ACC_SETS 64

// ---- one-time: build U' (16x16 complex, column phase folded) ----
__global__ __launch_bounds__(256) void qfc_prep(
    const float* __restrict__ vparams,
    float2* __restrict__ Ucg)           // [256]: U'[j][i] at Ucg[j*16+i]
{
    const int t = threadIdx.x;
    const int j = t >> 4, i = t & 15;   // column j, row i
    float ux = (i == j) ? 1.f : 0.f, uy = 0.f;
    for (int l = 0; l < 3; ++l) {
        for (int w = 0; w < 4; ++w) {
            const float* vp = vparams + (l * 4 + w) * 3;
            const int m = 8 >> w;       // wire w = state bit (3-w)
            float s, c;
            // RX: [c, -i s; -i s, c]
            __sincosf(0.5f * vp[0], &s, &c);
            {
                float ox = __shfl_xor(ux, m);
                float oy = __shfl_xor(uy, m);
                float nx = c * ux + s * oy;
                float ny = c * uy - s * ox;
                ux = nx; uy = ny;
            }
            // RY: [c, -s; s, c]
            __sincosf(0.5f * vp[1], &s, &c);
            {
                float ox = __shfl_xor(ux, m);
                float oy = __shfl_xor(uy, m);
                float sg = (i & m) ? s : -s;
                ux = c * ux + sg * ox;
                uy = c * uy + sg * oy;
            }
            // RZ: diag(e^{-it/2}, e^{it/2})
            __sincosf(0.5f * vp[2], &s, &c);
            {
                float sg = (i & m) ? s : -s;
                float nx = ux * c - sg * uy;
                float ny = uy * c + sg * ux;
                ux = nx; uy = ny;
            }
        }
        // CNOT chain: control bit (3-w), target bit (2-w)
        for (int w = 0; w < 3; ++w) {
            int mc = 8 >> w, mt = 4 >> w;
            float ox = __shfl_xor(ux, mt);
            float oy = __shfl_xor(uy, mt);
            if (i & mc) { ux = ox; uy = oy; }
        }
    }
    // fold column phase (-i)^popcount(j)
    int pc = __popc(j) & 3;
    float px, py;
    if (pc == 0)      { px =  ux; py =  uy; }
    else if (pc == 1) { px =  uy; py = -ux; }
    else if (pc == 2) { px = -ux; py = -uy; }
    else              { px = -uy; py =  ux; }
    Ucg[t] = make_float2(px, py);
}

__global__ __launch_bounds__(256) void qfc_main(
    const float* __restrict__ x,
    const float* __restrict__ W,
    const float* __restrict__ bias,
    const float2* __restrict__ Ucg,
    float* __restrict__ out,
    double* __restrict__ acc,   // [ACC_SETS][8]: 4 sums, 4 sumsq
    int B)
{
    __shared__ float  lds_img[IMG_PER_BLOCK * USED_F];  // 43008 B
    __shared__ float2 Uc[256];
    __shared__ float  pooled_s[256];                    // [g][cell]
    __shared__ float  bsum[4], bsq[4];

    const int t   = threadIdx.x;
    const int blk = blockIdx.x;

    if (t < 4) { bsum[t] = 0.f; bsq[t] = 0.f; }
    Uc[t] = Ucg[t];   // 2KB coalesced, L2-hit

    // ---- Phase 1: coalesced staging of 16 images (rows 0..23 only) ----
    {
        const float4* x4   = (const float4*)x;
        float4*       lds4 = (float4*)lds_img;
        #pragma unroll
        for (int k = 0; k < 11; ++k) {
            int q = t + k * 256;
            if (q < TOT4) {
                int g   = q / IMG_F4_USED;
                int r4  = q - g * IMG_F4_USED;
                int img = blk * IMG_PER_BLOCK + g;
                if (img < B) lds4[q] = x4[img * (IMG_F / 4) + r4];
            }
        }
    }
    __syncthreads();

    // ---- Phase 2: pooling. thread t -> image g = t>>4, cell = t&15 ----
    {
        const int g = t >> 4, cell = t & 15;
        const int ci = cell >> 2, cj = cell & 3;
        const float* base = lds_img + g * USED_F + ci * 6 * 28 + cj * 6;
        float sum = 0.f;
        #pragma unroll
        for (int r = 0; r < 6; ++r) {
            const float2* p2 = (const float2*)(base + r * 28);
            float2 a = p2[0], b2 = p2[1], c2 = p2[2];
            sum += a.x + a.y + b2.x + b2.y + c2.x + c2.y;
        }
        pooled_s[t] = sum * (1.0f / 36.0f);
    }
    __syncthreads();

    // ---- Phase 3: per-sample circuit. thread t -> image g, row i ----
    {
        const int g = t >> 4, i = t & 15;
        const float* pl = pooled_s + g * 16;
        float f0 = bias[0], f1 = bias[1], f2 = bias[2], f3 = bias[3];
        #pragma unroll
        for (int k = 0; k < 16; ++k) {
            float p = pl[k];
            f0 += p * W[k * 4 + 0];
            f1 += p * W[k * 4 + 1];
            f2 += p * W[k * 4 + 2];
            f3 += p * W[k * 4 + 3];
        }
        float c0, s0, c1, s1, c2, s2, c3, s3;
        __sincosf(0.5f * f0, &s0, &c0);
        __sincosf(0.5f * f1, &s1, &c1);
        __sincosf(0.5f * f2, &s2, &c2);
        __sincosf(0.5f * f3, &s3, &c3);
        // r_j = AB[j>>2] * CD[j&3]; bit3=wire0 ... bit0=wire3
        float AB[4] = { c0 * c1, c0 * s1, s0 * c1, s0 * s1 };
        float CD[4] = { c2 * c3, c2 * s3, s2 * c3, s2 * s3 };
        float yx = 0.f, yy = 0.f;
        #pragma unroll
        for (int j = 0; j < 16; ++j) {
            float r = AB[j >> 2] * CD[j & 3];
            float2 u = Uc[j * 16 + i];
            yx += u.x * r;
            yy += u.y * r;
        }
        float q = yx * yx + yy * yy;
        // 16-lane Walsh-Hadamard: lane m gets sum_i (-1)^popcount(i&m) q_i
        #pragma unroll
        for (int d = 1; d <= 8; d <<= 1) {
            float o = __shfl_xor(q, d);
            q = (i & d) ? (o - q) : (o + q);
        }
        int img = blk * IMG_PER_BLOCK + g;
        if ((i == 1 || i == 2 || i == 4 || i == 8) && img < B) {
            int w = (i == 8) ? 0 : (i == 4) ? 1 : (i == 2) ? 2 : 3;
            out[img * 4 + w] = q;       // raw <Z_w>, normalized in kernel 2
            atomicAdd(&bsum[w], q);
            atomicAdd(&bsq[w],  q * q);
        }
    }
    __syncthreads();

    if (t < 4) {
        int s = blk & (ACC_SETS - 1);
        atomicAdd(&acc[s * 8 + t],     (double)bsum[t]);
        atomicAdd(&acc[s * 8 + 4 + t], (double)bsq[t]);
    }
}

__global__ __launch_bounds__(256) void qfc_bn(
    float* __restrict__ out,
    const double* __restrict__ acc,
    const float* __restrict__ gamma,
    const float* __restrict__ beta,
    int B)
{
    __shared__ double tot_s[8];
    __shared__ float  mu_s[4], sc_s[4], bt_s[4];
    const int t = threadIdx.x;
    if (t < 8) {
        double tot = 0.0;
        for (int s = 0; s < ACC_SETS; ++s) tot += acc[s * 8 + t];
        tot_s[t] = tot;
    }
    __syncthreads();
    if (t < 4) {
        double invB = 1.0 / (double)B;
        double mu   = tot_s[t] * invB;
        double var  = tot_s[4 + t] * invB - mu * mu;
        mu_s[t] = (float)mu;
        sc_s[t] = (float)(1.0 / sqrt(var + 1e-5)) * gamma[t];
        bt_s[t] = beta[t];
    }
    __syncthreads();
    int idx = blockIdx.x * blockDim.x + t;
    if (idx < B) {
        float4* o4 = (float4*)out;
        float4 v = o4[idx];
        v.x = (v.x - mu_s[0]) * sc_s[0] + bt_s[0];
        v.y = (v.y - mu_s[1]) * sc_s[1] + bt_s[1];
        v.z = (v.z - mu_s[2]) * sc_s[2] + bt_s[2];
        v.w = (v.w - mu_s[3]) * sc_s[3] + bt_s[3];
        o4[idx] = v;
    }
}

extern "C" void kernel_launch(void* const* d_in, const int* in_sizes, int n_in,
                              void* d_out, int out_size, void* d_ws, size_t ws_size,
                              hipStream_t stream) {
    const float* x       = (const float*)d_in[0];
    const float* W       = (const float*)d_in[1];
    const float* b       = (const float*)d_in[2];
    const float* vparams = (const float*)d_in[3];
    const float* gamma   = (const float*)d_in[4];
    const float* beta    = (const float*)d_in[5];
    float* out = (float*)d_out;
    const int B = in_sizes[0] / IMG_F;

    double* acc = (double*)d_ws;                        // 64*8 doubles = 4KB
    float2* Ucg = (float2*)((char*)d_ws + ACC_SETS * 8 * sizeof(double)); // 2KB

    hipMemsetAsync(acc, 0, ACC_SETS * 8 * sizeof(double), stream);
    qfc_prep<<<1, 256, 0, stream>>>(vparams, Ucg);

    int nblk1 = (B + IMG_PER_BLOCK - 1) / IMG_PER_BLOCK;
    qfc_main<<<nblk1, 256, 0, stream>>>(x, W, b, Ucg, out, acc, B);

    int nblk2 = (B + 255) / 256;
    qfc_bn<<<nblk2, 256, 0, stream>>>(out, acc, gamma, beta, B);
}

// Round 3
// 292.967 us; speedup vs baseline: 1.0349x; 1.0257x over previous
//
#include <hip/hip_runtime.h>
#include <math.h>

// QFCModel: avgpool(6x6) -> linear(16->4) -> 4-qubit circuit -> <Z> -> batchnorm
//
// |psi> = U_var * |enc(f)>, U_var fixed 16x16 complex (from vparams).
// enc[j] = r_j * (-i)^popcount(j), r_j real product of cos/sin half-angles.
// Fold phase into U columns => y_i = sum_j U'[i][j] * r_j  (real multiplier).
// <Z_w> = Walsh coefficient m=1<<(3-w) of q_i = |y_i|^2 (16-lane shfl butterfly).
//
// R3: stage only 24x24 (144 float4/img, row starts float4-aligned) -> LDS 36KB
// -> 4 blocks/CU (was 3); pool->feats exchange via intra-wave shfl (drop LDS
// pooled array + one barrier); acc-zeroing folded into qfc_prep (one fewer
// dispatch). HBM fetch unchanged (~176MB — the 16B row gaps free no 64B line).

#define IMG_PER_BLOCK 16
#define IMG_F 784            // floats per image (28*28)
#define IMG_F4 196           // float4s per image
#define ROW_F4 6             // float4s per staged row (cols 0..23)
#define STG_F4 144           // float4s staged per image (24 rows * 6)
#define STG_F 576            // floats staged per image (24*24)
#define TOT4 (IMG_PER_BLOCK * STG_F4)   // 2304 = 9*256 exactly
#define ACC_SETS 64

// ---- one-time: build U' (16x16 complex, column phase folded) + zero acc ----
__global__ __launch_bounds__(256) void qfc_prep(
    const float* __restrict__ vparams,
    float2* __restrict__ Ucg,           // [256]: U'[j][i] at Ucg[j*16+i]
    double* __restrict__ acc)           // [ACC_SETS*8]
{
    const int t = threadIdx.x;
    acc[t] = 0.0;
    acc[t + 256] = 0.0;
    const int j = t >> 4, i = t & 15;   // column j, row i
    float ux = (i == j) ? 1.f : 0.f, uy = 0.f;
    for (int l = 0; l < 3; ++l) {
        for (int w = 0; w < 4; ++w) {
            const float* vp = vparams + (l * 4 + w) * 3;
            const int m = 8 >> w;       // wire w = state bit (3-w)
            float s, c;
            // RX: [c, -i s; -i s, c]
            __sincosf(0.5f * vp[0], &s, &c);
            {
                float ox = __shfl_xor(ux, m);
                float oy = __shfl_xor(uy, m);
                float nx = c * ux + s * oy;
                float ny = c * uy - s * ox;
                ux = nx; uy = ny;
            }
            // RY: [c, -s; s, c]
            __sincosf(0.5f * vp[1], &s, &c);
            {
                float ox = __shfl_xor(ux, m);
                float oy = __shfl_xor(uy, m);
                float sg = (i & m) ? s : -s;
                ux = c * ux + sg * ox;
                uy = c * uy + sg * oy;
            }
            // RZ: diag(e^{-it/2}, e^{it/2})
            __sincosf(0.5f * vp[2], &s, &c);
            {
                float sg = (i & m) ? s : -s;
                float nx = ux * c - sg * uy;
                float ny = uy * c + sg * ux;
                ux = nx; uy = ny;
            }
        }
        // CNOT chain: control bit (3-w), target bit (2-w)
        for (int w = 0; w < 3; ++w) {
            int mc = 8 >> w, mt = 4 >> w;
            float ox = __shfl_xor(ux, mt);
            float oy = __shfl_xor(uy, mt);
            if (i & mc) { ux = ox; uy = oy; }
        }
    }
    // fold column phase (-i)^popcount(j)
    int pc = __popc(j) & 3;
    float px, py;
    if (pc == 0)      { px =  ux; py =  uy; }
    else if (pc == 1) { px =  uy; py = -ux; }
    else if (pc == 2) { px = -ux; py = -uy; }
    else              { px = -uy; py =  ux; }
    Ucg[t] = make_float2(px, py);
}

__global__ __launch_bounds__(256) void qfc_main(
    const float* __restrict__ x,
    const float* __restrict__ W,
    const float* __restrict__ bias,
    const float2* __restrict__ Ucg,
    float* __restrict__ out,
    double* __restrict__ acc,   // [ACC_SETS][8]: 4 sums, 4 sumsq
    int B)
{
    __shared__ float  lds_img[IMG_PER_BLOCK * STG_F];   // 36864 B
    __shared__ float2 Uc[256];                          // 2048 B
    __shared__ float  bsum[4], bsq[4];

    const int t   = threadIdx.x;
    const int blk = blockIdx.x;

    if (t < 4) { bsum[t] = 0.f; bsq[t] = 0.f; }
    Uc[t] = Ucg[t];   // 2KB coalesced, L2-hit

    // ---- Phase 1: stage 16 images, rows 0..23 cols 0..23 (float4-aligned) ----
    {
        const float4* x4   = (const float4*)x;
        float4*       lds4 = (float4*)lds_img;
        #pragma unroll
        for (int k = 0; k < 9; ++k) {               // 9*256 == TOT4 exactly
            int q    = t + k * 256;
            int g    = q / STG_F4;
            int r4   = q - g * STG_F4;
            int row  = r4 / ROW_F4;
            int col4 = r4 - row * ROW_F4;
            int img  = blk * IMG_PER_BLOCK + g;
            if (img < B)
                lds4[q] = x4[img * IMG_F4 + row * 7 + col4];
        }
    }
    __syncthreads();

    // ---- Phase 2: pooling. thread t -> image g = t>>4, cell = t&15 ----
    float pv;
    {
        const int g = t >> 4, cell = t & 15;
        const int ci = cell >> 2, cj = cell & 3;
        const float* base = lds_img + g * STG_F + ci * 6 * 24 + cj * 6;
        float sum = 0.f;
        #pragma unroll
        for (int r = 0; r < 6; ++r) {
            const float2* p2 = (const float2*)(base + r * 24);
            float2 a = p2[0], b2 = p2[1], c2 = p2[2];
            sum += a.x + a.y + b2.x + b2.y + c2.x + c2.y;
        }
        pv = sum * (1.0f / 36.0f);
    }
    // pooled value for (g, cell=k) lives in wave lane (t&48)|k — no barrier

    // ---- Phase 3: per-sample circuit. thread t -> image g, row i ----
    {
        const int g = t >> 4, i = t & 15;
        float f0 = bias[0], f1 = bias[1], f2 = bias[2], f3 = bias[3];
        #pragma unroll
        for (int k = 0; k < 16; ++k) {
            float p = __shfl(pv, (t & 48) | k, 64);
            f0 += p * W[k * 4 + 0];
            f1 += p * W[k * 4 + 1];
            f2 += p * W[k * 4 + 2];
            f3 += p * W[k * 4 + 3];
        }
        float c0, s0, c1, s1, c2, s2, c3, s3;
        __sincosf(0.5f * f0, &s0, &c0);
        __sincosf(0.5f * f1, &s1, &c1);
        __sincosf(0.5f * f2, &s2, &c2);
        __sincosf(0.5f * f3, &s3, &c3);
        // r_j = AB[j>>2] * CD[j&3]; bit3=wire0 ... bit0=wire3
        float AB[4] = { c0 * c1, c0 * s1, s0 * c1, s0 * s1 };
        float CD[4] = { c2 * c3, c2 * s3, s2 * c3, s2 * s3 };
        float yx = 0.f, yy = 0.f;
        #pragma unroll
        for (int j = 0; j < 16; ++j) {
            float r = AB[j >> 2] * CD[j & 3];
            float2 u = Uc[j * 16 + i];
            yx += u.x * r;
            yy += u.y * r;
        }
        float q = yx * yx + yy * yy;
        // 16-lane Walsh-Hadamard: lane m gets sum_i (-1)^popcount(i&m) q_i
        #pragma unroll
        for (int d = 1; d <= 8; d <<= 1) {
            float o = __shfl_xor(q, d);
            q = (i & d) ? (o - q) : (o + q);
        }
        int img = blk * IMG_PER_BLOCK + g;
        if ((i == 1 || i == 2 || i == 4 || i == 8) && img < B) {
            int w = (i == 8) ? 0 : (i == 4) ? 1 : (i == 2) ? 2 : 3;
            out[img * 4 + w] = q;       // raw <Z_w>, normalized in kernel 2
            atomicAdd(&bsum[w], q);
            atomicAdd(&bsq[w],  q * q);
        }
    }
    __syncthreads();

    if (t < 4) {
        int s = blk & (ACC_SETS - 1);
        atomicAdd(&acc[s * 8 + t],     (double)bsum[t]);
        atomicAdd(&acc[s * 8 + 4 + t], (double)bsq[t]);
    }
}

__global__ __launch_bounds__(256) void qfc_bn(
    float* __restrict__ out,
    const double* __restrict__ acc,
    const float* __restrict__ gamma,
    const float* __restrict__ beta,
    int B)
{
    __shared__ double tot_s[8];
    __shared__ float  mu_s[4], sc_s[4], bt_s[4];
    const int t = threadIdx.x;
    if (t < 8) {
        double tot = 0.0;
        for (int s = 0; s < ACC_SETS; ++s) tot += acc[s * 8 + t];
        tot_s[t] = tot;
    }
    __syncthreads();
    if (t < 4) {
        double invB = 1.0 / (double)B;
        double mu   = tot_s[t] * invB;
        double var  = tot_s[4 + t] * invB - mu * mu;
        mu_s[t] = (float)mu;
        sc_s[t] = (float)(1.0 / sqrt(var + 1e-5)) * gamma[t];
        bt_s[t] = beta[t];
    }
    __syncthreads();
    int idx = blockIdx.x * blockDim.x + t;
    if (idx < B) {
        float4* o4 = (float4*)out;
        float4 v = o4[idx];
        v.x = (v.x - mu_s[0]) * sc_s[0] + bt_s[0];
        v.y = (v.y - mu_s[1]) * sc_s[1] + bt_s[1];
        v.z = (v.z - mu_s[2]) * sc_s[2] + bt_s[2];
        v.w = (v.w - mu_s[3]) * sc_s[3] + bt_s[3];
        o4[idx] = v;
    }
}

extern "C" void kernel_launch(void* const* d_in, const int* in_sizes, int n_in,
                              void* d_out, int out_size, void* d_ws, size_t ws_size,
                              hipStream_t stream) {
    const float* x       = (const float*)d_in[0];
    const float* W       = (const float*)d_in[1];
    const float* b       = (const float*)d_in[2];
    const float* vparams = (const float*)d_in[3];
    const float* gamma   = (const float*)d_in[4];
    const float* beta    = (const float*)d_in[5];
    float* out = (float*)d_out;
    const int B = in_sizes[0] / IMG_F;

    double* acc = (double*)d_ws;                        // 64*8 doubles = 4KB
    float2* Ucg = (float2*)((char*)d_ws + ACC_SETS * 8 * sizeof(double)); // 2KB

    qfc_prep<<<1, 256, 0, stream>>>(vparams, Ucg, acc);

    int nblk1 = (B + IMG_PER_BLOCK - 1) / IMG_PER_BLOCK;
    qfc_main<<<nblk1, 256, 0, stream>>>(x, W, b, Ucg, out, acc, B);

    int nblk2 = (B + 255) / 256;
    qfc_bn<<<nblk2, 256, 0, stream>>>(out, acc, gamma, beta, B);
}